// Round 9
// baseline (214.335 us; speedup 1.0000x reference)
//
#include <hip/hip_runtime.h>
#include <hip/hip_bf16.h>
#include <hip/hip_cooperative_groups.h>

namespace cg = cooperative_groups;

// Problem: B=4, N=512, D=1024, H=256. Inputs fp32, OUTPUT fp32.
//   o[b,n,h]     = sum_d x[b,n,d]*W1[h,d] + b1[h]                  (2048x256, K=1024)
//   out[b,i,j,c] = sum_h (o[b,i,h]*W2[c,h]) * o[b,j,h] + b2[c]     (per b,c: 512x512, K=256)
//
// R8: fused cooperative kernel, grid = 256 blocks (1 block/CU guaranteed co-resident
// under any occupancy metric — R7's 512-block coop launch was silently rejected,
// almost certainly CooperativeLaunchTooLarge from a 64KiB-based occupancy calc).
//   Phase A: split-K GEMM -> bf16 partials P; each block runs 2 units (64mT x 8kT).
//   Phase B: o = bf16(sum_k P + b1), 8 elems/thread.
//   Phase C: 64x64 supertile bilinear (round-6 stage2, grid-256 mapping).

typedef __attribute__((ext_vector_type(8))) short bf16x8;   // 8 bf16 = 4 VGPRs
typedef __attribute__((ext_vector_type(4))) short bf16x4;   // 4 bf16 = 2 VGPRs
typedef __attribute__((ext_vector_type(4))) float f32x4;
typedef __attribute__((ext_vector_type(2))) float f32x2;

__device__ __forceinline__ unsigned short f2bf(float f) {
    __hip_bfloat16 h = __float2bfloat16(f);   // RNE
    unsigned short s;
    __builtin_memcpy(&s, &h, 2);
    return s;
}

__device__ __forceinline__ float bf2f(unsigned short b) {
    unsigned int u = ((unsigned int)b) << 16;
    float f;
    __builtin_memcpy(&f, &u, 4);
    return f;
}

__device__ __forceinline__ bf16x4 cvt4(f32x4 v) {
    bf16x4 r;
    r[0] = (short)f2bf(v[0]); r[1] = (short)f2bf(v[1]);
    r[2] = (short)f2bf(v[2]); r[3] = (short)f2bf(v[3]);
    return r;
}

#define S1_LD 72    // phase-A LDS row pitch (shorts)
#define S2_LD 264   // phase-C LDS row pitch (shorts): 256 + 8 pad

// LDS union: phase A = 32*72*2 + 256*72*2 = 41472 B; phase C = 64*264*2 = 33792 B.
#define SMEM_BYTES 41472

__global__ __launch_bounds__(256) void fused_kernel(
    const float* __restrict__ x,        // [2048][1024]
    const float* __restrict__ W1,       // [256][1024]
    const float* __restrict__ b1,       // [256]
    const float* __restrict__ W2,       // [2][256]
    const float* __restrict__ b2,       // [2]
    unsigned short* __restrict__ P,     // ws: [8][2048][256] bf16 partials
    unsigned short* __restrict__ o,     // ws: [2048][256] bf16
    float* __restrict__ out)            // [4][512][512][2] fp32
{
    __shared__ alignas(16) unsigned char smem[SMEM_BYTES];
    unsigned short* xs  = (unsigned short*)smem;            // A: [32][S1_LD]
    unsigned short* ws_ = (unsigned short*)(smem + 4608);   // A: [256][S1_LD]
    unsigned short* js  = (unsigned short*)smem;            // C: [64][S2_LD]

    cg::grid_group grid = cg::this_grid();

    const int tid  = threadIdx.x;
    const int lane = tid & 63;
    const int wave = tid >> 6;
    const int blk  = blockIdx.x;        // 0..255
    const int l15  = lane & 15;
    const int quad = lane >> 4;

    // ================= Phase A: split-K GEMM -> bf16 partials =================
    // 512 units = 64 mTiles(32 rows) x 8 kChunks(128); block runs units blk, blk+256.
    #pragma unroll 1
    for (int u = 0; u < 2; ++u) {
        const int unit = blk + u * 256;
        const int kT = unit & 7;
        const int mT = unit >> 3;                    // 0..63, 32 rows each

        f32x4 acc[2][4];
        #pragma unroll
        for (int f = 0; f < 2; ++f)
            #pragma unroll
            for (int g = 0; g < 4; ++g)
                acc[f][g] = (f32x4){0.f, 0.f, 0.f, 0.f};

        #pragma unroll 1
        for (int p = 0; p < 2; ++p) {                // two 64-wide K phases
            const int k0 = kT * 128 + p * 64;
            if (p | u) __syncthreads();              // drain prior LDS reads

            #pragma unroll
            for (int i = 0; i < 2; ++i) {            // x tile: 32x64
                const int idx = i * 256 + tid;
                const int row = idx >> 4;
                const int c4  = idx & 15;
                f32x4 v = *(const f32x4*)(x + (mT * 32 + row) * 1024 + k0 + c4 * 4);
                *(bf16x4*)(&xs[row * S1_LD + c4 * 4]) = cvt4(v);
            }
            #pragma unroll 8
            for (int i = 0; i < 16; ++i) {           // W1 tile: 256x64
                const int idx = i * 256 + tid;
                const int row = idx >> 4;
                const int c4  = idx & 15;
                f32x4 v = *(const f32x4*)(W1 + row * 1024 + k0 + c4 * 4);
                *(bf16x4*)(&ws_[row * S1_LD + c4 * 4]) = cvt4(v);
            }
            __syncthreads();

            #pragma unroll
            for (int s = 0; s < 2; ++s) {
                bf16x8 a[2], b[4];
                #pragma unroll
                for (int f = 0; f < 2; ++f)
                    a[f] = *(const bf16x8*)(&xs[(f * 16 + l15) * S1_LD + s * 32 + quad * 8]);
                #pragma unroll
                for (int g = 0; g < 4; ++g)
                    b[g] = *(const bf16x8*)(&ws_[(wave * 64 + g * 16 + l15) * S1_LD + s * 32 + quad * 8]);
                #pragma unroll
                for (int f = 0; f < 2; ++f)
                    #pragma unroll
                    for (int g = 0; g < 4; ++g)
                        acc[f][g] = __builtin_amdgcn_mfma_f32_16x16x32_bf16(a[f], b[g], acc[f][g], 0, 0, 0);
            }
        }

        unsigned short* Pk = P + kT * (2048 * 256);
        #pragma unroll
        for (int f = 0; f < 2; ++f) {
            #pragma unroll
            for (int g = 0; g < 4; ++g) {
                const int h = wave * 64 + g * 16 + l15;
                #pragma unroll
                for (int r = 0; r < 4; ++r) {
                    const int m = mT * 32 + f * 16 + quad * 4 + r;
                    Pk[m * 256 + h] = f2bf(acc[f][g][r]);
                }
            }
        }
    }

    __threadfence();
    grid.sync();

    // ================= Phase B: o = bf16(sum_k P + b1) =================
    {
        const int base = (blk * 256 + tid) * 8;      // 256*256*8 = 524288 = 2048*256
        const int h0 = base & 255;
        float s[8];
        {
            f32x4 blo = *(const f32x4*)(b1 + h0);
            f32x4 bhi = *(const f32x4*)(b1 + h0 + 4);
            #pragma unroll
            for (int j = 0; j < 4; ++j) { s[j] = blo[j]; s[4 + j] = bhi[j]; }
        }
        #pragma unroll
        for (int kt = 0; kt < 8; ++kt) {
            bf16x8 v = *(const bf16x8*)(P + kt * (2048 * 256) + base);
            #pragma unroll
            for (int j = 0; j < 8; ++j)
                s[j] += bf2f((unsigned short)v[j]);
        }
        bf16x8 r;
        #pragma unroll
        for (int j = 0; j < 8; ++j)
            r[j] = (short)f2bf(s[j]);
        *(bf16x8*)(o + base) = r;
    }

    __threadfence();
    grid.sync();
    __syncthreads();   // js aliases xs/ws_: ensure all lds reads from phase A done (they are; cheap safety)

    // ================= Phase C: out = bilinear(o) =================
    // 256 blocks = b(4) x iS(8) x jS(8). Supertile 64 i x 64 j; wave owns 16 i-rows.
    {
        const int b  = blk >> 6;            // 4
        const int iS = (blk >> 3) & 7;      // 8
        const int jS = blk & 7;             // 8

        // Stage j-rows o[b][jS*64 .. +63][0:256] into LDS (2048 16B chunks, 8/thread).
        const unsigned short* jbase = o + (b * 512 + jS * 64) * 256;
        #pragma unroll
        for (int i = 0; i < 8; ++i) {
            const int idx = i * 256 + tid;      // 0..2047 = 64 rows x 32 chunks
            const int row = idx >> 5;
            const int c8  = idx & 31;
            *(bf16x8*)(&js[row * S2_LD + c8 * 8]) = *(const bf16x8*)(jbase + row * 256 + c8 * 8);
        }
        __syncthreads();

        const unsigned short* irow = o + ((b * 512 + iS * 64 + wave * 16 + l15) * 256) + quad * 8;
        const float* w20p = W2 + quad * 8;
        const float* w21p = W2 + 256 + quad * 8;

        f32x4 acc0[4], acc1[4];
        #pragma unroll
        for (int g = 0; g < 4; ++g) {
            acc0[g] = (f32x4){0.f, 0.f, 0.f, 0.f};
            acc1[g] = (f32x4){0.f, 0.f, 0.f, 0.f};
        }

        #pragma unroll
        for (int s = 0; s < 8; ++s) {
            const int k = s * 32;
            bf16x8 oi = *(const bf16x8*)(irow + k);
            f32x4 wlo0 = *(const f32x4*)(w20p + k);
            f32x4 whi0 = *(const f32x4*)(w20p + k + 4);
            f32x4 wlo1 = *(const f32x4*)(w21p + k);
            f32x4 whi1 = *(const f32x4*)(w21p + k + 4);
            bf16x8 a0, a1;
            #pragma unroll
            for (int j = 0; j < 4; ++j) {
                const float olo = bf2f((unsigned short)oi[j]);
                const float ohi = bf2f((unsigned short)oi[4 + j]);
                a0[j]     = (short)f2bf(olo * wlo0[j]);
                a0[4 + j] = (short)f2bf(ohi * whi0[j]);
                a1[j]     = (short)f2bf(olo * wlo1[j]);
                a1[4 + j] = (short)f2bf(ohi * whi1[j]);
            }
            #pragma unroll
            for (int g = 0; g < 4; ++g) {
                bf16x8 bj = *(const bf16x8*)(&js[(g * 16 + l15) * S2_LD + k + quad * 8]);
                acc0[g] = __builtin_amdgcn_mfma_f32_16x16x32_bf16(a0, bj, acc0[g], 0, 0, 0);
                acc1[g] = __builtin_amdgcn_mfma_f32_16x16x32_bf16(a1, bj, acc1[g], 0, 0, 0);
            }
        }

        const float bias0 = b2[0];
        const float bias1 = b2[1];
        #pragma unroll
        for (int g = 0; g < 4; ++g) {
            const int j = jS * 64 + g * 16 + l15;           // n-index = lane&15
            #pragma unroll
            for (int r = 0; r < 4; ++r) {
                const int i = iS * 64 + wave * 16 + quad * 4 + r;   // m-index
                f32x2 v;
                v[0] = acc0[g][r] + bias0;
                v[1] = acc1[g][r] + bias1;
                *(f32x2*)(out + (((b * 512 + i) * 512) + j) * 2) = v;
            }
        }
    }
}

extern "C" void kernel_launch(void* const* d_in, const int* in_sizes, int n_in,
                              void* d_out, int out_size, void* d_ws, size_t ws_size,
                              hipStream_t stream) {
    const float* x  = (const float*)d_in[0];   // [4,512,1024] fp32
    const float* W1 = (const float*)d_in[1];   // [256,1024] fp32
    const float* b1 = (const float*)d_in[2];   // [256] fp32
    const float* W2 = (const float*)d_in[3];   // [2,256] fp32
    const float* b2 = (const float*)d_in[4];   // [2] fp32
    float* out = (float*)d_out;                // [4,512,512,2] fp32

    // ws layout: o bf16 [2048][256] = 1 MB @ 0; P bf16 [8][2048][256] = 8 MB @ 1 MB
    unsigned short* o = (unsigned short*)d_ws;
    unsigned short* P = (unsigned short*)((char*)d_ws + (1u << 20));

    void* args[] = { (void*)&x, (void*)&W1, (void*)&b1, (void*)&W2, (void*)&b2,
                     (void*)&P, (void*)&o, (void*)&out };
    hipLaunchCooperativeKernel((const void*)fused_kernel, dim3(256), dim3(256),
                               args, 0, stream);
}

// Round 10
// 86.551 us; speedup vs baseline: 2.4764x; 2.4764x over previous
//
#include <hip/hip_runtime.h>
#include <hip/hip_bf16.h>

// Problem: B=4, N=512, D=1024, H=256. Inputs fp32, OUTPUT fp32.
//   o[b,n,h]     = sum_d x[b,n,d]*W1[h,d] + b1[h]                  (2048x256, K=1024)
//   out[b,i,j,c] = sum_h (o[b,i,h]*W2[c,h]) * o[b,j,h] + b2[c]     (per b,c: 512x512, K=256)
//
// R9: cooperative fusion reverted (grid.sync costs ~100 us on 8-XCD gfx950).
// Two kernels:
//   s1_direct: NO split-K. 512 blocks = 128 mT(16 rows) x 4 hT(64 h), full K=1024,
//     single fp32 accum chain -> o directly. Kills P round-trip (16 MB HBM),
//     the s1_reduce kernel, and one launch gap. blk = hT*128 + mT so the 4
//     hT-peers of an mT land on the SAME XCD (128 % 8 == 0) -> x re-reads are
//     L2 hits; W1 (1 MB) is L2-resident per XCD.
//   stage2: unchanged from R6/R7 (passing, ~5 us): 64x64 supertile, LDS j-rows.

typedef __attribute__((ext_vector_type(8))) short bf16x8;   // 8 bf16 = 4 VGPRs
typedef __attribute__((ext_vector_type(4))) short bf16x4;   // 4 bf16 = 2 VGPRs
typedef __attribute__((ext_vector_type(4))) float f32x4;
typedef __attribute__((ext_vector_type(2))) float f32x2;

__device__ __forceinline__ unsigned short f2bf(float f) {
    __hip_bfloat16 h = __float2bfloat16(f);   // RNE
    unsigned short s;
    __builtin_memcpy(&s, &h, 2);
    return s;
}

__device__ __forceinline__ float bf2f(unsigned short b) {
    unsigned int u = ((unsigned int)b) << 16;
    float f;
    __builtin_memcpy(&f, &u, 4);
    return f;
}

__device__ __forceinline__ bf16x4 cvt4(f32x4 v) {
    bf16x4 r;
    r[0] = (short)f2bf(v[0]); r[1] = (short)f2bf(v[1]);
    r[2] = (short)f2bf(v[2]); r[3] = (short)f2bf(v[3]);
    return r;
}

#define S1_LD 72    // LDS row pitch (shorts): 16B-aligned, 36-bank stride

// ---------------- Stage 1: o = bf16(x @ W1^T + b1), no split-K ----------------
__global__ __launch_bounds__(256) void s1_direct(
    const float* __restrict__ x,     // [2048][1024]
    const float* __restrict__ W1,    // [256][1024]
    const float* __restrict__ b1,    // [256]
    unsigned short* __restrict__ o)  // [2048][256] bf16
{
    __shared__ unsigned short xs[16 * S1_LD];    // 2304 B
    __shared__ unsigned short ws_[64 * S1_LD];   // 9216 B
    const int tid  = threadIdx.x;
    const int lane = tid & 63;
    const int wave = tid >> 6;
    const int mT = blockIdx.x & 127;             // 128 m-tiles of 16 rows
    const int hT = blockIdx.x >> 7;              // 4 h-tiles of 64
    const int m0 = mT * 16;
    const int h0 = hT * 64;
    const int l15 = lane & 15;
    const int quad = lane >> 4;

    f32x4 acc = {0.f, 0.f, 0.f, 0.f};            // wave owns h-slice h0+wave*16..+15

    #pragma unroll 1
    for (int p = 0; p < 16; ++p) {               // 16 K-phases of 64
        const int k0 = p * 64;
        if (p) __syncthreads();                  // drain MFMA LDS reads

        // x tile 16x64: 256 f32x4, 1/thread; lanes cover 256B runs coalesced.
        {
            const int row = tid >> 4;
            const int c4  = tid & 15;
            f32x4 v = *(const f32x4*)(x + (m0 + row) * 1024 + k0 + c4 * 4);
            *(bf16x4*)(&xs[row * S1_LD + c4 * 4]) = cvt4(v);
        }
        // W1 tile 64x64: 1024 f32x4, 4/thread.
        #pragma unroll
        for (int i = 0; i < 4; ++i) {
            const int idx = i * 256 + tid;
            const int row = idx >> 4;
            const int c4  = idx & 15;
            f32x4 v = *(const f32x4*)(W1 + (h0 + row) * 1024 + k0 + c4 * 4);
            *(bf16x4*)(&ws_[row * S1_LD + c4 * 4]) = cvt4(v);
        }
        __syncthreads();

        #pragma unroll
        for (int s = 0; s < 2; ++s) {            // two k32 steps
            bf16x8 a = *(const bf16x8*)(&xs[l15 * S1_LD + s * 32 + quad * 8]);
            bf16x8 b = *(const bf16x8*)(&ws_[(wave * 16 + l15) * S1_LD + s * 32 + quad * 8]);
            acc = __builtin_amdgcn_mfma_f32_16x16x32_bf16(a, b, acc, 0, 0, 0);
        }
    }

    // D layout: col(h)=lane&15, row(m)=quad*4+reg
    const int h = h0 + wave * 16 + l15;
    const float bias = b1[h];
    #pragma unroll
    for (int r = 0; r < 4; ++r) {
        const int m = m0 + quad * 4 + r;
        o[m * 256 + h] = f2bf(acc[r] + bias);
    }
}

// ---------------- Stage 2: 64x64 supertile, LDS j-rows (unchanged R6/R7) ----------------
#define S2_LD 264   // shorts per LDS row (256 + 8 pad); 64*264*2 = 33792 B

__global__ __launch_bounds__(256) void stage2_kernel(
    const unsigned short* __restrict__ o,    // [4][512][256] bf16
    const float* __restrict__ W2,            // [2][256] fp32
    const float* __restrict__ b2,            // [2] fp32
    float* __restrict__ out)                 // [4][512][512][2] fp32
{
    __shared__ unsigned short js[64 * S2_LD];
    const int tid  = threadIdx.x;
    const int lane = tid & 63;
    const int wave = tid >> 6;
    const int blk  = blockIdx.x;        // 0..255
    const int b  = blk >> 6;            // 4
    const int iS = (blk >> 3) & 7;      // 8
    const int jS = blk & 7;             // 8
    const int l15 = lane & 15;
    const int quad = lane >> 4;

    // Stage j-rows o[b][jS*64 .. +63][0:256] into LDS (coalesced 16B copies).
    const unsigned short* jbase = o + (b * 512 + jS * 64) * 256;
    #pragma unroll
    for (int i = 0; i < 8; ++i) {
        const int idx = i * 256 + tid;      // 0..2047 = 64 rows x 32 chunks
        const int row = idx >> 5;
        const int c8  = idx & 31;
        *(bf16x8*)(&js[row * S2_LD + c8 * 8]) = *(const bf16x8*)(jbase + row * 256 + c8 * 8);
    }
    __syncthreads();

    const unsigned short* irow = o + ((b * 512 + iS * 64 + wave * 16 + l15) * 256) + quad * 8;
    const float* w20p = W2 + quad * 8;
    const float* w21p = W2 + 256 + quad * 8;

    f32x4 acc0[4], acc1[4];
    #pragma unroll
    for (int g = 0; g < 4; ++g) {
        acc0[g] = (f32x4){0.f, 0.f, 0.f, 0.f};
        acc1[g] = (f32x4){0.f, 0.f, 0.f, 0.f};
    }

    #pragma unroll
    for (int s = 0; s < 8; ++s) {
        const int k = s * 32;
        bf16x8 oi = *(const bf16x8*)(irow + k);
        f32x4 wlo0 = *(const f32x4*)(w20p + k);
        f32x4 whi0 = *(const f32x4*)(w20p + k + 4);
        f32x4 wlo1 = *(const f32x4*)(w21p + k);
        f32x4 whi1 = *(const f32x4*)(w21p + k + 4);
        bf16x8 a0, a1;
        #pragma unroll
        for (int j = 0; j < 4; ++j) {
            const float olo = bf2f((unsigned short)oi[j]);
            const float ohi = bf2f((unsigned short)oi[4 + j]);
            a0[j]     = (short)f2bf(olo * wlo0[j]);
            a0[4 + j] = (short)f2bf(ohi * whi0[j]);
            a1[j]     = (short)f2bf(olo * wlo1[j]);
            a1[4 + j] = (short)f2bf(ohi * whi1[j]);
        }
        #pragma unroll
        for (int g = 0; g < 4; ++g) {
            bf16x8 bj = *(const bf16x8*)(&js[(g * 16 + l15) * S2_LD + k + quad * 8]);
            acc0[g] = __builtin_amdgcn_mfma_f32_16x16x32_bf16(a0, bj, acc0[g], 0, 0, 0);
            acc1[g] = __builtin_amdgcn_mfma_f32_16x16x32_bf16(a1, bj, acc1[g], 0, 0, 0);
        }
    }

    const float bias0 = b2[0];
    const float bias1 = b2[1];
    #pragma unroll
    for (int g = 0; g < 4; ++g) {
        const int j = jS * 64 + g * 16 + l15;           // n-index = lane&15
        #pragma unroll
        for (int r = 0; r < 4; ++r) {
            const int i = iS * 64 + wave * 16 + quad * 4 + r;   // m-index
            f32x2 v;
            v[0] = acc0[g][r] + bias0;
            v[1] = acc1[g][r] + bias1;
            *(f32x2*)(out + (((b * 512 + i) * 512) + j) * 2) = v;
        }
    }
}

extern "C" void kernel_launch(void* const* d_in, const int* in_sizes, int n_in,
                              void* d_out, int out_size, void* d_ws, size_t ws_size,
                              hipStream_t stream) {
    const float* x  = (const float*)d_in[0];   // [4,512,1024] fp32
    const float* W1 = (const float*)d_in[1];   // [256,1024] fp32
    const float* b1 = (const float*)d_in[2];   // [256] fp32
    const float* W2 = (const float*)d_in[3];   // [2,256] fp32
    const float* b2 = (const float*)d_in[4];   // [2] fp32
    float* out = (float*)d_out;                // [4,512,512,2] fp32

    // ws: o bf16 [2048][256] = 1 MB
    unsigned short* o = (unsigned short*)d_ws;

    s1_direct    <<<512, 256, 0, stream>>>(x, W1, b1, o);
    stage2_kernel<<<256, 256, 0, stream>>>(o, W2, b2, out);
}

// Round 11
// 81.005 us; speedup vs baseline: 2.6459x; 1.0685x over previous
//
#include <hip/hip_runtime.h>
#include <hip/hip_bf16.h>

// Problem: B=4, N=512, D=1024, H=256. Inputs fp32, OUTPUT fp32.
//   o[b,n,h]     = sum_d x[b,n,d]*W1[h,d] + b1[h]                  (2048x256, K=1024)
//   out[b,i,j,c] = sum_h (o[b,i,h]*W2[c,h]) * o[b,j,h] + b2[c]     (per b,c: 512x512, K=256)
//
// R10 = R7 pipeline (best known, 84.4) + u-precompute (ws_size proven 256 MiB):
//   s1_gemm:   split-K 64mT x 8kT -> bf16 partials P        [identical to R7]
//   s1_reduce: o = bf16(sum P + b1); u_c = bf16(o * W2[c])  [extended: +u0,u1]
//   stage2:    64x64 supertile; A-frags loaded from u0/u1 (kills ~40 VALU per
//              8 MFMA that R7 spent rebuilding u_c per k-step).

typedef __attribute__((ext_vector_type(8))) short bf16x8;   // 8 bf16 = 4 VGPRs
typedef __attribute__((ext_vector_type(4))) short bf16x4;   // 4 bf16 = 2 VGPRs
typedef __attribute__((ext_vector_type(4))) float f32x4;
typedef __attribute__((ext_vector_type(2))) float f32x2;

__device__ __forceinline__ unsigned short f2bf(float f) {
    __hip_bfloat16 h = __float2bfloat16(f);   // RNE
    unsigned short s;
    __builtin_memcpy(&s, &h, 2);
    return s;
}

__device__ __forceinline__ float bf2f(unsigned short b) {
    unsigned int u = ((unsigned int)b) << 16;
    float f;
    __builtin_memcpy(&f, &u, 4);
    return f;
}

__device__ __forceinline__ bf16x4 cvt4(f32x4 v) {
    bf16x4 r;
    r[0] = (short)f2bf(v[0]); r[1] = (short)f2bf(v[1]);
    r[2] = (short)f2bf(v[2]); r[3] = (short)f2bf(v[3]);
    return r;
}

// ---------------- Stage 1a: split-K GEMM -> bf16 partials (R7, unchanged) ----------------
#define S1_LD 72

__global__ __launch_bounds__(256) void s1_gemm(
    const float* __restrict__ x,        // [2048][1024]
    const float* __restrict__ W1,       // [256][1024]
    unsigned short* __restrict__ P)     // [8][2048][256] bf16 partials
{
    __shared__ unsigned short xs[32 * S1_LD];    // 4608 B
    __shared__ unsigned short ws_[256 * S1_LD];  // 36864 B
    const int tid  = threadIdx.x;
    const int lane = tid & 63;
    const int wave = tid >> 6;
    const int kT = blockIdx.x & 7;
    const int mT = blockIdx.x >> 3;              // 0..63, 32 rows each
    const int l15 = lane & 15;
    const int quad = lane >> 4;

    f32x4 acc[2][4];
    #pragma unroll
    for (int f = 0; f < 2; ++f)
        #pragma unroll
        for (int g = 0; g < 4; ++g)
            acc[f][g] = (f32x4){0.f, 0.f, 0.f, 0.f};

    for (int p = 0; p < 2; ++p) {                // two 64-wide K phases
        const int k0 = kT * 128 + p * 64;
        if (p) __syncthreads();

        #pragma unroll
        for (int i = 0; i < 2; ++i) {            // x tile: 32x64
            const int idx = i * 256 + tid;
            const int row = idx >> 4;
            const int c4  = idx & 15;
            f32x4 v = *(const f32x4*)(x + (mT * 32 + row) * 1024 + k0 + c4 * 4);
            *(bf16x4*)(&xs[row * S1_LD + c4 * 4]) = cvt4(v);
        }
        #pragma unroll 8
        for (int i = 0; i < 16; ++i) {           // W1 tile: 256x64
            const int idx = i * 256 + tid;
            const int row = idx >> 4;
            const int c4  = idx & 15;
            f32x4 v = *(const f32x4*)(W1 + row * 1024 + k0 + c4 * 4);
            *(bf16x4*)(&ws_[row * S1_LD + c4 * 4]) = cvt4(v);
        }
        __syncthreads();

        #pragma unroll
        for (int s = 0; s < 2; ++s) {
            bf16x8 a[2], b[4];
            #pragma unroll
            for (int f = 0; f < 2; ++f)
                a[f] = *(const bf16x8*)(&xs[(f * 16 + l15) * S1_LD + s * 32 + quad * 8]);
            #pragma unroll
            for (int g = 0; g < 4; ++g)
                b[g] = *(const bf16x8*)(&ws_[(wave * 64 + g * 16 + l15) * S1_LD + s * 32 + quad * 8]);
            #pragma unroll
            for (int f = 0; f < 2; ++f)
                #pragma unroll
                for (int g = 0; g < 4; ++g)
                    acc[f][g] = __builtin_amdgcn_mfma_f32_16x16x32_bf16(a[f], b[g], acc[f][g], 0, 0, 0);
        }
    }

    unsigned short* Pk = P + kT * (2048 * 256);
    #pragma unroll
    for (int f = 0; f < 2; ++f) {
        #pragma unroll
        for (int g = 0; g < 4; ++g) {
            const int h = wave * 64 + g * 16 + l15;
            #pragma unroll
            for (int r = 0; r < 4; ++r) {
                const int m = mT * 32 + f * 16 + quad * 4 + r;
                Pk[m * 256 + h] = f2bf(acc[f][g][r]);
            }
        }
    }
}

// ---------------- Stage 1b: o = bf16(sum_k P + b1); u_c = bf16(o * W2[c]) ----------------
// 256 blocks x 256 threads; each thread handles 8 consecutive h-elements.
// u computed from the ROUNDED o -> stage2 operands bit-identical to R7's
// on-the-fly build (absmax prediction: exactly 0.0390625).
__global__ __launch_bounds__(256) void s1_reduce(
    const unsigned short* __restrict__ P,  // [8][2048][256] bf16
    const float* __restrict__ b1,          // [256]
    const float* __restrict__ W2,          // [2][256]
    unsigned short* __restrict__ o,        // [2048][256] bf16
    unsigned short* __restrict__ u0,       // [2048][256] bf16
    unsigned short* __restrict__ u1)       // [2048][256] bf16
{
    const int base = (blockIdx.x * 256 + threadIdx.x) * 8;   // elem idx, 8 each
    const int h0 = base & 255;
    float s[8];
    {
        f32x4 blo = *(const f32x4*)(b1 + h0);
        f32x4 bhi = *(const f32x4*)(b1 + h0 + 4);
        #pragma unroll
        for (int j = 0; j < 4; ++j) { s[j] = blo[j]; s[4 + j] = bhi[j]; }
    }
    #pragma unroll
    for (int kt = 0; kt < 8; ++kt) {
        bf16x8 v = *(const bf16x8*)(P + kt * (2048 * 256) + base);
        #pragma unroll
        for (int j = 0; j < 8; ++j)
            s[j] += bf2f((unsigned short)v[j]);
    }
    f32x4 w0lo = *(const f32x4*)(W2 + h0);
    f32x4 w0hi = *(const f32x4*)(W2 + h0 + 4);
    f32x4 w1lo = *(const f32x4*)(W2 + 256 + h0);
    f32x4 w1hi = *(const f32x4*)(W2 + 256 + h0 + 4);
    bf16x8 ro, r0, r1;
    #pragma unroll
    for (int j = 0; j < 8; ++j) {
        const unsigned short ob = f2bf(s[j]);
        const float of = bf2f(ob);              // rounded o, matches R7 operand path
        const float w0 = (j < 4) ? w0lo[j] : w0hi[j - 4];
        const float w1 = (j < 4) ? w1lo[j] : w1hi[j - 4];
        ro[j] = (short)ob;
        r0[j] = (short)f2bf(of * w0);
        r1[j] = (short)f2bf(of * w1);
    }
    *(bf16x8*)(o  + base) = ro;
    *(bf16x8*)(u0 + base) = r0;
    *(bf16x8*)(u1 + base) = r1;
}

// ---------------- Stage 2 v3: 64x64 supertile, LDS j-rows, u-frag A-loads ----------------
#define S2_LD 264   // shorts per LDS row (256 + 8 pad); 64*264*2 = 33792 B

__global__ __launch_bounds__(256) void stage2_kernel(
    const unsigned short* __restrict__ o,    // [4][512][256] bf16
    const unsigned short* __restrict__ u0,   // [4][512][256] bf16
    const unsigned short* __restrict__ u1,   // [4][512][256] bf16
    const float* __restrict__ b2,            // [2] fp32
    float* __restrict__ out)                 // [4][512][512][2] fp32
{
    __shared__ unsigned short js[64 * S2_LD];
    const int tid  = threadIdx.x;
    const int lane = tid & 63;
    const int wave = tid >> 6;
    const int blk  = blockIdx.x;        // 0..255
    const int b  = blk >> 6;            // 4
    const int iS = (blk >> 3) & 7;      // 8
    const int jS = blk & 7;             // 8
    const int l15 = lane & 15;
    const int quad = lane >> 4;

    // Stage j-rows o[b][jS*64 .. +63][0:256] into LDS (coalesced 16B copies).
    const unsigned short* jbase = o + (b * 512 + jS * 64) * 256;
    #pragma unroll
    for (int i = 0; i < 8; ++i) {
        const int idx = i * 256 + tid;      // 0..2047 = 64 rows x 32 chunks
        const int row = idx >> 5;
        const int c8  = idx & 31;
        *(bf16x8*)(&js[row * S2_LD + c8 * 8]) = *(const bf16x8*)(jbase + row * 256 + c8 * 8);
    }
    __syncthreads();

    const int ioff = ((b * 512 + iS * 64 + wave * 16 + l15) * 256) + quad * 8;
    const unsigned short* irow0 = u0 + ioff;
    const unsigned short* irow1 = u1 + ioff;

    f32x4 acc0[4], acc1[4];
    #pragma unroll
    for (int g = 0; g < 4; ++g) {
        acc0[g] = (f32x4){0.f, 0.f, 0.f, 0.f};
        acc1[g] = (f32x4){0.f, 0.f, 0.f, 0.f};
    }

    #pragma unroll
    for (int s = 0; s < 8; ++s) {
        const int k = s * 32;
        bf16x8 a0 = *(const bf16x8*)(irow0 + k);
        bf16x8 a1 = *(const bf16x8*)(irow1 + k);
        #pragma unroll
        for (int g = 0; g < 4; ++g) {
            bf16x8 bj = *(const bf16x8*)(&js[(g * 16 + l15) * S2_LD + k + quad * 8]);
            acc0[g] = __builtin_amdgcn_mfma_f32_16x16x32_bf16(a0, bj, acc0[g], 0, 0, 0);
            acc1[g] = __builtin_amdgcn_mfma_f32_16x16x32_bf16(a1, bj, acc1[g], 0, 0, 0);
        }
    }

    const float bias0 = b2[0];
    const float bias1 = b2[1];
    #pragma unroll
    for (int g = 0; g < 4; ++g) {
        const int j = jS * 64 + g * 16 + l15;           // n-index = lane&15
        #pragma unroll
        for (int r = 0; r < 4; ++r) {
            const int i = iS * 64 + wave * 16 + quad * 4 + r;   // m-index
            f32x2 v;
            v[0] = acc0[g][r] + bias0;
            v[1] = acc1[g][r] + bias1;
            *(f32x2*)(out + (((b * 512 + i) * 512) + j) * 2) = v;
        }
    }
}

extern "C" void kernel_launch(void* const* d_in, const int* in_sizes, int n_in,
                              void* d_out, int out_size, void* d_ws, size_t ws_size,
                              hipStream_t stream) {
    const float* x  = (const float*)d_in[0];   // [4,512,1024] fp32
    const float* W1 = (const float*)d_in[1];   // [256,1024] fp32
    const float* b1 = (const float*)d_in[2];   // [256] fp32
    const float* W2 = (const float*)d_in[3];   // [2,256] fp32
    const float* b2 = (const float*)d_in[4];   // [2] fp32
    float* out = (float*)d_out;                // [4,512,512,2] fp32

    // ws layout (256 MiB available):
    //   o  bf16 [2048][256] @ 0      (1 MB)
    //   u0 bf16 [2048][256] @ 1 MB   (1 MB)
    //   u1 bf16 [2048][256] @ 2 MB   (1 MB)
    //   P  bf16 [8][2048][256] @ 3 MB (8 MB)
    unsigned short* o  = (unsigned short*)d_ws;
    unsigned short* u0 = (unsigned short*)((char*)d_ws + (1u << 20));
    unsigned short* u1 = (unsigned short*)((char*)d_ws + (2u << 20));
    unsigned short* P  = (unsigned short*)((char*)d_ws + (3u << 20));

    s1_gemm  <<<512, 256, 0, stream>>>(x, W1, P);
    s1_reduce<<<256, 256, 0, stream>>>(P, b1, W2, o, u0, u1);
    stage2_kernel<<<256, 256, 0, stream>>>(o, u0, u1, b2, out);
}